// Round 12
// baseline (411.187 us; speedup 1.0000x reference)
//
#include <hip/hip_runtime.h>
#include <hip/hip_bf16.h>
#include <math.h>

#define B_ 8
#define W_ 1024
#define D_ 1024
#define R_ 64

typedef __hip_bfloat16 bf16;
typedef __attribute__((ext_vector_type(8))) short bf16x8;   // MFMA A/B frag (4 VGPRs)
typedef __attribute__((ext_vector_type(4))) float f32x4;    // MFMA C/D frag

__device__ __forceinline__ float tof(bf16 x) { return __bfloat162float(x); }
__device__ __forceinline__ short f2bs(float f) {
    bf16 b = __float2bfloat16(f);
    return *(short*)&b;
}

// async global->LDS, 16 bytes/lane; LDS dest = wave-uniform base + lane*16
__device__ __forceinline__ void async16(const void* g, void* l) {
    __builtin_amdgcn_global_load_lds(
        (const __attribute__((address_space(1))) unsigned int*)g,
        (__attribute__((address_space(3))) unsigned int*)l,
        16, 0, 0);
}

// ---------------------------------------------------------------------------
// RMSNorm: one block (256 threads) per row of D_=1024. fp32 in, bf16 out.
// ---------------------------------------------------------------------------
__global__ __launch_bounds__(256)
void rmsnorm_kernel(const float* __restrict__ src, const float* __restrict__ scale,
                    bf16* __restrict__ dst) {
    int row = blockIdx.x;
    const float* x = src + (size_t)row * D_;
    bf16* y = dst + (size_t)row * D_;
    float xv[4];
    float ss = 0.f;
#pragma unroll
    for (int it = 0; it < 4; ++it) {
        int d = threadIdx.x + it * 256;
        xv[it] = x[d];
        ss += xv[it] * xv[it];
    }
#pragma unroll
    for (int off = 32; off; off >>= 1) ss += __shfl_down(ss, off, 64);
    __shared__ float red[4];
    __shared__ float invs;
    int lane = threadIdx.x & 63, wid = threadIdx.x >> 6;
    if (lane == 0) red[wid] = ss;
    __syncthreads();
    if (threadIdx.x == 0) {
        float t = red[0] + red[1] + red[2] + red[3];
        invs = rsqrtf(t / (float)D_ + 1e-8f);
    }
    __syncthreads();
    float inv = invs;
#pragma unroll
    for (int it = 0; it < 4; ++it) {
        int d = threadIdx.x + it * 256;
        y[d] = __float2bfloat16(xv[it] * inv * scale[d]);
    }
}

// ---------------------------------------------------------------------------
// 64x64 LDS-tiled transpose: src[b][j][d] -> dst[b][d][j]  (bf16)
// ---------------------------------------------------------------------------
__global__ __launch_bounds__(256)
void transpose_kernel(const bf16* __restrict__ src, bf16* __restrict__ dst) {
    int b = blockIdx.z;
    int j0 = blockIdx.x * 64, d0 = blockIdx.y * 64;
    __shared__ short Ts[64][72];
    const bf16* S = src + (size_t)b * W_ * D_;
    bf16* Dd = dst + (size_t)b * W_ * D_;
    int tid = threadIdx.x;
    int r = tid >> 3, c = (tid & 7) * 8;
#pragma unroll
    for (int p = 0; p < 2; ++p) {
        int j = r + p * 32;
        bf16x8 vv = *(const bf16x8*)&S[(size_t)(j0 + j) * D_ + d0 + c];
#pragma unroll
        for (int e = 0; e < 8; ++e) Ts[j][c + e] = vv[e];
    }
    __syncthreads();
#pragma unroll
    for (int p = 0; p < 2; ++p) {
        int d = r + p * 32;
        bf16x8 vv;
#pragma unroll
        for (int e = 0; e < 8; ++e) vv[e] = Ts[c + e][d];
        *(bf16x8*)&Dd[(size_t)(d0 + d) * W_ + j0 + c] = vv;
    }
}

// ---------------------------------------------------------------------------
// uvT[r][d] (bf16, [128][1024]) from u[d][64] (z=0) and v[d][64] (z=1).
// ---------------------------------------------------------------------------
__global__ __launch_bounds__(256)
void uvT_kernel(const float* __restrict__ u, const float* __restrict__ v,
                bf16* __restrict__ uvT) {
    int g = blockIdx.z;
    int d0 = blockIdx.x * 64;
    const float* src = g ? v : u;
    __shared__ float Ts[64][65];
    int tid = threadIdx.x;
#pragma unroll
    for (int e = 0; e < 16; ++e) {
        int idx = tid + e * 256;
        int drow = idx >> 6, rcol = idx & 63;
        Ts[drow][rcol] = src[(size_t)(d0 + drow) * 64 + rcol];
    }
    __syncthreads();
#pragma unroll
    for (int e = 0; e < 16; ++e) {
        int idx = tid + e * 256;
        int orow = idx >> 6, ocol = idx & 63;
        uvT[(size_t)(g * 64 + orow) * D_ + d0 + ocol] = __float2bfloat16(Ts[ocol][orow]);
    }
}

// ---------------------------------------------------------------------------
// fp32 -> bf16 convert of the three weight matrices in ONE launch.
// ranges: [0, D^2) proj, [D^2, 3D^2) up, [3D^2, 5D^2) down.
// ---------------------------------------------------------------------------
__global__ __launch_bounds__(256)
void convert3_kernel(const float* __restrict__ proj, const float* __restrict__ up,
                     const float* __restrict__ down,
                     bf16* __restrict__ projb, bf16* __restrict__ upb,
                     bf16* __restrict__ downb) {
    size_t idx = ((size_t)blockIdx.x * 256 + threadIdx.x) * 8;
    const size_t DD = (size_t)D_ * D_;
    const float* src; bf16* dst; size_t off;
    if (idx < DD)          { src = proj; dst = projb; off = idx; }
    else if (idx < 3 * DD) { src = up;   dst = upb;   off = idx - DD; }
    else                   { src = down; dst = downb; off = idx - 3 * DD; }
    float4 f0 = *(const float4*)(src + off);
    float4 f1 = *(const float4*)(src + off + 4);
    bf16x8 p;
    p[0] = f2bs(f0.x); p[1] = f2bs(f0.y); p[2] = f2bs(f0.z); p[3] = f2bs(f0.w);
    p[4] = f2bs(f1.x); p[5] = f2bs(f1.y); p[6] = f2bs(f1.z); p[7] = f2bs(f1.w);
    *(bf16x8*)(dst + off) = p;
}

// ---------------------------------------------------------------------------
// qk epilogue: sum SK=4 fp32 partials, l2norm halves, gamma^{+/-i} -> qg, kg.
// ---------------------------------------------------------------------------
__global__ __launch_bounds__(128)
void qk_epilogue_kernel(const float* __restrict__ qkraw,
                        const float* __restrict__ decay_logit,
                        float* __restrict__ qg, float* __restrict__ kg) {
    int row = blockIdx.x;          // b*W + i
    int i = row & (W_ - 1);
    int t = threadIdx.x;
    int r = t & 63;
    bool isK = t >= 64;
    const size_t PS = (size_t)B_ * W_ * 128;   // partial stride
    size_t off = (size_t)row * 128 + t;
    float val = qkraw[off] + qkraw[PS + off] + qkraw[2 * PS + off] + qkraw[3 * PS + off];
    float sq = val * val;
#pragma unroll
    for (int o = 32; o; o >>= 1) sq += __shfl_xor(sq, o, 64);
    val = val / fmaxf(sqrtf(sq), 1e-8f);

    float dl = decay_logit[r];
    float gamma = 0.15f + 0.85f * (1.f / (1.f + expf(-dl)));
    float lg = logf(gamma);
    float e = isK ? expf(-(float)i * lg) : expf((float)i * lg);
    float o = val * e;
    if (isK) kg[(size_t)row * R_ + r] = o;
    else     qg[(size_t)row * R_ + r] = o;
}

// ---------------------------------------------------------------------------
// M[b,i,j] = (j<=i) ? gate*k_base[i,j] + alpha * dot(qg[b,i,:], kg[b,j,:]) : 0
// ---------------------------------------------------------------------------
__global__ __launch_bounds__(256)
void buildM_kernel(const float* __restrict__ qg, const float* __restrict__ kg,
                   const float* __restrict__ k_base,
                   const float* __restrict__ gate_logit,
                   const float* __restrict__ alpha_logit,
                   bf16* __restrict__ M) {
    int b = blockIdx.z;
    int ti = blockIdx.y, tj = blockIdx.x;
    int i0 = ti * 32, j0 = tj * 32;
    int tx = threadIdx.x, ty = threadIdx.y;
    bf16* Mb = M + (size_t)b * W_ * W_;
    const bf16 zero = __float2bfloat16(0.f);

    if (tj > ti) {
#pragma unroll
        for (int a = 0; a < 2; ++a)
#pragma unroll
            for (int c = 0; c < 2; ++c)
                Mb[(size_t)(i0 + ty * 2 + a) * W_ + (j0 + tx * 2 + c)] = zero;
        return;
    }

    __shared__ float Qs[32][65];
    __shared__ float Ks[32][65];
    int tid = ty * 16 + tx;
    for (int e = tid; e < 32 * 64; e += 256) {
        int rr = e & 63, row = e >> 6;
        Qs[row][rr] = qg[((size_t)b * W_ + i0 + row) * R_ + rr];
        Ks[row][rr] = kg[((size_t)b * W_ + j0 + row) * R_ + rr];
    }
    __syncthreads();

    float acc[2][2] = {{0.f, 0.f}, {0.f, 0.f}};
#pragma unroll 8
    for (int r = 0; r < 64; ++r) {
        float qa = Qs[ty * 2 + 0][r], qb = Qs[ty * 2 + 1][r];
        float ka = Ks[tx * 2 + 0][r], kb = Ks[tx * 2 + 1][r];
        acc[0][0] += qa * ka; acc[0][1] += qa * kb;
        acc[1][0] += qb * ka; acc[1][1] += qb * kb;
    }

    float gate  = 1.f / (1.f + expf(-(*gate_logit)));
    float alpha = 1.f / (1.f + expf(-(*alpha_logit)));  // ALPHA_CAP = 1
#pragma unroll
    for (int a = 0; a < 2; ++a) {
#pragma unroll
        for (int c = 0; c < 2; ++c) {
            int i = i0 + ty * 2 + a, j = j0 + tx * 2 + c;
            float vkb = k_base[(size_t)i * W_ + j];
            float out = (j <= i) ? (gate * vkb + alpha * acc[a][c]) : 0.f;
            Mb[(size_t)i * W_ + j] = __float2bfloat16(out);
        }
    }
}

// ---------------------------------------------------------------------------
// MFMA GEMM: C[m,n] = sum_k A[m,k]*B[n,k]  (A, B bf16, k-major)
// *** Round-11 change: BM=64 x BN=128 (was 128x128). Rounds 8-11 showed the
// 512-block grids cap at 2 blocks/CU (22% occ) and depth-1 prefetch cannot
// cover ~900-cyc latency -> TLP is the only cover (m97 ran 4 blocks/CU).
// Shrinking BM (not BN!) doubles the grid while doubling re-reads of the
// SMALL B operand (weights, 2-4 MB -> per-XCD L2-resident), leaving the
// streamed 32 MB A operand's traffic unchanged (rounds 8/10 shrank BN and
// blew up A-traffic: FETCH 33->66/151 MB, regressed). ***
// 4 waves (2x2): wave tile 32x64 = 2x4 MFMA tiles of 16x16x32. LDS 24 KB.
// XOR-swizzled conflict-free async staging, hoisted pointers, LDS dbuf,
// one __syncthreads per iter (round-9 best-measured loop).
// Grid XCD-TRANSPOSED: x = M-stripe (count % 8 == 0), y = N-block ->
// XCD = x%8; A-stripe re-reads stay in one XCD's L2.
// SK>1: z = K-chunk, EPI must be 5 (partial store).  SK==1: z = batch.
// EPI 0: Cout bf16 = acc                      (batched store via sC)
// EPI 1: Cout fp32 = acc + bias[n] + Res[idx] (Res may alias Cout, same-idx)
// EPI 2: Cout bf16 = gelu_exact(acc + bias[n])
// EPI 5: Cout fp32 partial at z*sC            (deterministic split-K)
// ---------------------------------------------------------------------------
template<int EPI, int SK>
__global__ __launch_bounds__(256)
void mgemm_kernel(const bf16* __restrict__ A, const bf16* __restrict__ Bm,
                  const float* __restrict__ Res, const float* __restrict__ bias,
                  void* __restrict__ Cout,
                  int M, int N, int K,
                  long sA, long sB, long sC, int causal) {
    __shared__ __align__(16) short At[2][64 * 32];    //  8 KB
    __shared__ __align__(16) short Bt[2][128 * 32];   // 16 KB
    int z = blockIdx.z;
    const bf16* Ab = (SK > 1) ? A : A + (size_t)z * sA;
    const bf16* Bb = (SK > 1) ? Bm : Bm + (size_t)z * sB;
    int kchunk = K / SK;
    int kbeg = (SK > 1) ? z * kchunk : 0;
    int m0 = blockIdx.x * 64, n0 = blockIdx.y * 128;   // transposed grid
    int tid = threadIdx.x;
    int lane = tid & 63, wave = tid >> 6;
    int wy = wave >> 1, wx = wave & 1;
    int quad = lane >> 4, l15 = lane & 15;

    f32x4 acc[2][4];
#pragma unroll
    for (int i = 0; i < 2; ++i)
#pragma unroll
        for (int j = 0; j < 4; ++j)
            acc[i][j] = (f32x4){0.f, 0.f, 0.f, 0.f};

    int kend = kbeg + kchunk;
    if (SK == 1 && causal) kend = (m0 + 64 < K) ? m0 + 64 : K;
    int nIter = (kend - kbeg) >> 5;

    // staging geometry: each async16 covers 16 rows (64B/row of BK=32 bf16);
    // lane covers row base+(lane>>2), 16B chunk slot lane&3, source chunk
    // XOR-swizzled so LDS b128 reads are 2-way max (free).
    int srcChunk = ((lane & 3) ^ ((lane >> 3) & 3)) * 8;
    size_t rowA = (size_t)(m0 + wave * 16 + (lane >> 2)) * K;
    size_t rowB = (size_t)(n0 + wave * 16 + (lane >> 2)) * K;
    const bf16* aP0 = Ab + rowA + srcChunk + kbeg;          // A: 1 issue/wave
    const bf16* bP0 = Bb + rowB + srcChunk + kbeg;          // B: 2 issues/wave
    const bf16* bP1 = bP0 + (size_t)64 * K;
    short* dA0[2] = { &At[0][wave * 512],        &At[1][wave * 512] };
    short* dB0[2] = { &Bt[0][wave * 512],        &Bt[1][wave * 512] };
    short* dB1[2] = { &Bt[0][2048 + wave * 512], &Bt[1][2048 + wave * 512] };

    int rswz = (quad ^ ((l15 >> 1) & 3)) * 8;

    // prologue: stage tile 0 into buf 0
    async16(aP0, dA0[0]);
    async16(bP0, dB0[0]); async16(bP1, dB1[0]);
    aP0 += 32; bP0 += 32; bP1 += 32;
    __syncthreads();

    for (int it = 0; it < nIter; ++it) {
        int cur = it & 1;
        if (it + 1 < nIter) {
            int nxt = cur ^ 1;
            async16(aP0, dA0[nxt]);
            async16(bP0, dB0[nxt]); async16(bP1, dB1[nxt]);
            aP0 += 32; bP0 += 32; bP1 += 32;
        }
        bf16x8 af[2], bfr[4];
#pragma unroll
        for (int mi = 0; mi < 2; ++mi)
            af[mi] = *(const bf16x8*)&At[cur][(wy * 32 + mi * 16 + l15) * 32 + rswz];
#pragma unroll
        for (int ni = 0; ni < 4; ++ni)
            bfr[ni] = *(const bf16x8*)&Bt[cur][(wx * 64 + ni * 16 + l15) * 32 + rswz];
#pragma unroll
        for (int mi = 0; mi < 2; ++mi)
#pragma unroll
            for (int ni = 0; ni < 4; ++ni)
                acc[mi][ni] = __builtin_amdgcn_mfma_f32_16x16x32_bf16(
                    af[mi], bfr[ni], acc[mi][ni], 0, 0, 0);
        // one barrier/iter: (a) next-buf async complete, (b) cur reads done
        __syncthreads();
    }

    // ---- epilogue ----
#pragma unroll
    for (int ni = 0; ni < 4; ++ni) {
        int col = n0 + wx * 64 + ni * 16 + l15;
        float bv = (EPI == 1 || EPI == 2) ? bias[col] : 0.f;
#pragma unroll
        for (int mi = 0; mi < 2; ++mi) {
            int row0 = m0 + wy * 32 + mi * 16 + quad * 4;
#pragma unroll
            for (int r = 0; r < 4; ++r) {
                size_t idx = (size_t)(row0 + r) * N + col;
                float val = acc[mi][ni][r];
                if constexpr (EPI == 0) {
                    ((bf16*)Cout)[(size_t)z * sC + idx] = __float2bfloat16(val);
                } else if constexpr (EPI == 1) {
                    ((float*)Cout)[idx] = val + bv + Res[idx];
                } else if constexpr (EPI == 2) {
                    val += bv;
                    val = 0.5f * val * (1.f + erff(val * 0.70710678118654752f));
                    ((bf16*)Cout)[idx] = __float2bfloat16(val);
                } else {
                    ((float*)Cout)[(size_t)z * sC + idx] = val;
                }
            }
        }
    }
}

// ---------------------------------------------------------------------------
// Workspace (peak 62 MB):
//   [0,16)  : hnorm bf16 -> attn bf16 (step4 out) -> mnorm bf16 (step6 out)
//   [16,18) : uvT bf16 (dead after step 2) -> qg fp32 (written step 2b)
//   [18,20) : kg fp32
//   [20,36) : hnormT bf16            -+ tbuf bf16 [20,52) after step 4
//   [36,52) : qkraw fp32 4x4MB split-K partials (dead after 2b) -> Mbuf bf16
//   [52,54) : proj_w bf16   [54,58): up_w bf16   [58,62): down_w bf16
//   h1 lives in d_out (fp32); step 8 does same-index RMW (alias-safe).
// ---------------------------------------------------------------------------
extern "C" void kernel_launch(void* const* d_in, const int* in_sizes, int n_in,
                              void* d_out, int out_size, void* d_ws, size_t ws_size,
                              hipStream_t stream) {
    const float* h           = (const float*)d_in[0];
    const float* k_base      = (const float*)d_in[1];
    const float* decay_logit = (const float*)d_in[2];
    const float* gate_logit  = (const float*)d_in[3];
    const float* alpha_logit = (const float*)d_in[4];
    const float* u           = (const float*)d_in[5];
    const float* v           = (const float*)d_in[6];
    const float* proj_w      = (const float*)d_in[7];
    const float* proj_b      = (const float*)d_in[8];
    const float* norm1_scale = (const float*)d_in[9];
    const float* norm2_scale = (const float*)d_in[10];
    const float* up_w        = (const float*)d_in[11];
    const float* up_b        = (const float*)d_in[12];
    const float* down_w      = (const float*)d_in[13];
    const float* down_b      = (const float*)d_in[14];

    const size_t MB = 1048576;
    char* ws = (char*)d_ws;
    bf16*  hnorm   = (bf16*)(ws);                  // 16 MB
    bf16*  uvT     = (bf16*)(ws + 16 * MB);        // 256 KB (dead after step 2)
    float* qg      = (float*)(ws + 16 * MB);       //  2 MB (written step 2b)
    float* kg      = (float*)(ws + 18 * MB);       //  2 MB
    bf16*  hnormT  = (bf16*)(ws + 20 * MB);        // 16 MB
    float* qkraw   = (float*)(ws + 36 * MB);       // 16 MB partials (pre-buildM)
    bf16*  Mbuf    = (bf16*)(ws + 36 * MB);        // 16 MB (step 3 out)
    bf16*  proj_wb = (bf16*)(ws + 52 * MB);        //  2 MB
    bf16*  up_wb   = (bf16*)(ws + 54 * MB);        //  4 MB
    bf16*  down_wb = (bf16*)(ws + 58 * MB);        //  4 MB
    bf16*  attn    = hnorm;                        // [0,16) after qk GEMM
    bf16*  mnorm   = hnorm;
    bf16*  tbuf    = hnormT;                       // [20,52) after step 4
    float* h1      = (float*)d_out;

    // 0. weight conversions (single launch) + uvT
    convert3_kernel<<<5 * D_ * D_ / 2048, 256, 0, stream>>>(
        proj_w, up_w, down_w, proj_wb, up_wb, down_wb);
    uvT_kernel<<<dim3(D_ / 64, 1, 2), 256, 0, stream>>>(u, v, uvT);

    // 1. h_norm = rmsnorm(h, norm1_scale)
    rmsnorm_kernel<<<B_ * W_, 256, 0, stream>>>(h, norm1_scale, hnorm);

    // 1b. hnormT[b][d][j] = hnorm[b][j][d]
    transpose_kernel<<<dim3(W_ / 64, D_ / 64, B_), 256, 0, stream>>>(hnorm, hnormT);

    // 2. qkraw[z] = hnorm @ [u|v] K-chunk z (split-K=4, BM=64 -> 512 blocks)
    mgemm_kernel<5, 4><<<dim3(B_ * W_ / 64, 1, 4), 256, 0, stream>>>(
        hnorm, uvT, nullptr, nullptr, qkraw, B_ * W_, 128, D_,
        0, 0, (long)B_ * W_ * 128, 0);

    // 2b. sum partials, l2norm halves, gamma^{+/-i} -> qg, kg (fp32)
    qk_epilogue_kernel<<<B_ * W_, 128, 0, stream>>>(qkraw, decay_logit, qg, kg);

    // 3. M = causal * (gate*k_base + alpha*scores)
    buildM_kernel<<<dim3(W_ / 32, W_ / 32, B_), dim3(16, 16), 0, stream>>>(
        qg, kg, k_base, gate_logit, alpha_logit, Mbuf);

    // 4. attn = M @ hnorm  (B = hnormT, batched via z, causal, 1024 blocks)
    mgemm_kernel<0, 1><<<dim3(W_ / 64, D_ / 128, B_), 256, 0, stream>>>(
        Mbuf, hnormT, nullptr, nullptr, attn, W_, D_, W_,
        (long)W_ * W_, (long)W_ * D_, (long)W_ * D_, 1);

    // 5. h1 = h + attn @ proj_w^T + proj_b   -> d_out (fp32, 1024 blocks)
    mgemm_kernel<1, 1><<<dim3(B_ * W_ / 64, D_ / 128, 1), 256, 0, stream>>>(
        attn, proj_wb, h, proj_b, h1, B_ * W_, D_, D_, 0, 0, 0, 0);

    // 6. mnorm = rmsnorm(h1, norm2_scale)
    rmsnorm_kernel<<<B_ * W_, 256, 0, stream>>>(h1, norm2_scale, mnorm);

    // 7. t = gelu(mnorm @ up_w^T + up_b)     -> tbuf (bf16, 2048 blocks)
    mgemm_kernel<2, 1><<<dim3(B_ * W_ / 64, 2 * D_ / 128, 1), 256, 0, stream>>>(
        mnorm, up_wb, nullptr, up_b, tbuf, B_ * W_, 2 * D_, D_, 0, 0, 0, 0);

    // 8. out = h1 + t @ down_w^T + down_b  (h1 aliases d_out, 1024 blocks)
    mgemm_kernel<1, 1><<<dim3(B_ * W_ / 64, D_ / 128, 1), 256, 0, stream>>>(
        tbuf, down_wb, h1, down_b, (float*)d_out, B_ * W_, D_, 2 * D_, 0, 0, 0, 0);
}

// Round 13
// 362.541 us; speedup vs baseline: 1.1342x; 1.1342x over previous
//
#include <hip/hip_runtime.h>
#include <hip/hip_bf16.h>
#include <math.h>

#define B_ 8
#define W_ 1024
#define D_ 1024
#define R_ 64

typedef __hip_bfloat16 bf16;
typedef __attribute__((ext_vector_type(8))) short bf16x8;   // MFMA A/B frag (4 VGPRs)
typedef __attribute__((ext_vector_type(4))) float f32x4;    // MFMA C/D frag

__device__ __forceinline__ float tof(bf16 x) { return __bfloat162float(x); }
__device__ __forceinline__ short f2bs(float f) {
    bf16 b = __float2bfloat16(f);
    return *(short*)&b;
}

// async global->LDS, 16 bytes/lane; LDS dest = wave-uniform base + lane*16
__device__ __forceinline__ void async16(const void* g, void* l) {
    __builtin_amdgcn_global_load_lds(
        (const __attribute__((address_space(1))) unsigned int*)g,
        (__attribute__((address_space(3))) unsigned int*)l,
        16, 0, 0);
}

// ---------------------------------------------------------------------------
// RMSNorm: one block (256 threads) per row of D_=1024. fp32 in, bf16 out.
// ---------------------------------------------------------------------------
__global__ __launch_bounds__(256)
void rmsnorm_kernel(const float* __restrict__ src, const float* __restrict__ scale,
                    bf16* __restrict__ dst) {
    int row = blockIdx.x;
    const float* x = src + (size_t)row * D_;
    bf16* y = dst + (size_t)row * D_;
    float xv[4];
    float ss = 0.f;
#pragma unroll
    for (int it = 0; it < 4; ++it) {
        int d = threadIdx.x + it * 256;
        xv[it] = x[d];
        ss += xv[it] * xv[it];
    }
#pragma unroll
    for (int off = 32; off; off >>= 1) ss += __shfl_down(ss, off, 64);
    __shared__ float red[4];
    __shared__ float invs;
    int lane = threadIdx.x & 63, wid = threadIdx.x >> 6;
    if (lane == 0) red[wid] = ss;
    __syncthreads();
    if (threadIdx.x == 0) {
        float t = red[0] + red[1] + red[2] + red[3];
        invs = rsqrtf(t / (float)D_ + 1e-8f);
    }
    __syncthreads();
    float inv = invs;
#pragma unroll
    for (int it = 0; it < 4; ++it) {
        int d = threadIdx.x + it * 256;
        y[d] = __float2bfloat16(xv[it] * inv * scale[d]);
    }
}

// ---------------------------------------------------------------------------
// 64x64 LDS-tiled transpose: src[b][j][d] -> dst[b][d][j]  (bf16)
// ---------------------------------------------------------------------------
__global__ __launch_bounds__(256)
void transpose_kernel(const bf16* __restrict__ src, bf16* __restrict__ dst) {
    int b = blockIdx.z;
    int j0 = blockIdx.x * 64, d0 = blockIdx.y * 64;
    __shared__ short Ts[64][72];
    const bf16* S = src + (size_t)b * W_ * D_;
    bf16* Dd = dst + (size_t)b * W_ * D_;
    int tid = threadIdx.x;
    int r = tid >> 3, c = (tid & 7) * 8;
#pragma unroll
    for (int p = 0; p < 2; ++p) {
        int j = r + p * 32;
        bf16x8 vv = *(const bf16x8*)&S[(size_t)(j0 + j) * D_ + d0 + c];
#pragma unroll
        for (int e = 0; e < 8; ++e) Ts[j][c + e] = vv[e];
    }
    __syncthreads();
#pragma unroll
    for (int p = 0; p < 2; ++p) {
        int d = r + p * 32;
        bf16x8 vv;
#pragma unroll
        for (int e = 0; e < 8; ++e) vv[e] = Ts[c + e][d];
        *(bf16x8*)&Dd[(size_t)(d0 + d) * W_ + j0 + c] = vv;
    }
}

// ---------------------------------------------------------------------------
// uvT[r][d] (bf16, [128][1024]) from u[d][64] (z=0) and v[d][64] (z=1).
// ---------------------------------------------------------------------------
__global__ __launch_bounds__(256)
void uvT_kernel(const float* __restrict__ u, const float* __restrict__ v,
                bf16* __restrict__ uvT) {
    int g = blockIdx.z;
    int d0 = blockIdx.x * 64;
    const float* src = g ? v : u;
    __shared__ float Ts[64][65];
    int tid = threadIdx.x;
#pragma unroll
    for (int e = 0; e < 16; ++e) {
        int idx = tid + e * 256;
        int drow = idx >> 6, rcol = idx & 63;
        Ts[drow][rcol] = src[(size_t)(d0 + drow) * 64 + rcol];
    }
    __syncthreads();
#pragma unroll
    for (int e = 0; e < 16; ++e) {
        int idx = tid + e * 256;
        int orow = idx >> 6, ocol = idx & 63;
        uvT[(size_t)(g * 64 + orow) * D_ + d0 + ocol] = __float2bfloat16(Ts[ocol][orow]);
    }
}

// ---------------------------------------------------------------------------
// fp32 -> bf16 convert of the three weight matrices in ONE launch.
// ---------------------------------------------------------------------------
__global__ __launch_bounds__(256)
void convert3_kernel(const float* __restrict__ proj, const float* __restrict__ up,
                     const float* __restrict__ down,
                     bf16* __restrict__ projb, bf16* __restrict__ upb,
                     bf16* __restrict__ downb) {
    size_t idx = ((size_t)blockIdx.x * 256 + threadIdx.x) * 8;
    const size_t DD = (size_t)D_ * D_;
    const float* src; bf16* dst; size_t off;
    if (idx < DD)          { src = proj; dst = projb; off = idx; }
    else if (idx < 3 * DD) { src = up;   dst = upb;   off = idx - DD; }
    else                   { src = down; dst = downb; off = idx - 3 * DD; }
    float4 f0 = *(const float4*)(src + off);
    float4 f1 = *(const float4*)(src + off + 4);
    bf16x8 p;
    p[0] = f2bs(f0.x); p[1] = f2bs(f0.y); p[2] = f2bs(f0.z); p[3] = f2bs(f0.w);
    p[4] = f2bs(f1.x); p[5] = f2bs(f1.y); p[6] = f2bs(f1.z); p[7] = f2bs(f1.w);
    *(bf16x8*)(dst + off) = p;
}

// ---------------------------------------------------------------------------
// qk epilogue: sum SK=4 fp32 partials, l2norm halves, gamma^{+/-i} -> qg, kg.
// ---------------------------------------------------------------------------
__global__ __launch_bounds__(128)
void qk_epilogue_kernel(const float* __restrict__ qkraw,
                        const float* __restrict__ decay_logit,
                        float* __restrict__ qg, float* __restrict__ kg) {
    int row = blockIdx.x;          // b*W + i
    int i = row & (W_ - 1);
    int t = threadIdx.x;
    int r = t & 63;
    bool isK = t >= 64;
    const size_t PS = (size_t)B_ * W_ * 128;   // partial stride
    size_t off = (size_t)row * 128 + t;
    float val = qkraw[off] + qkraw[PS + off] + qkraw[2 * PS + off] + qkraw[3 * PS + off];
    float sq = val * val;
#pragma unroll
    for (int o = 32; o; o >>= 1) sq += __shfl_xor(sq, o, 64);
    val = val / fmaxf(sqrtf(sq), 1e-8f);

    float dl = decay_logit[r];
    float gamma = 0.15f + 0.85f * (1.f / (1.f + expf(-dl)));
    float lg = logf(gamma);
    float e = isK ? expf(-(float)i * lg) : expf((float)i * lg);
    float o = val * e;
    if (isK) kg[(size_t)row * R_ + r] = o;
    else     qg[(size_t)row * R_ + r] = o;
}

// ---------------------------------------------------------------------------
// M[b,i,j] = (j<=i) ? gate*k_base[i,j] + alpha * dot(qg[b,i,:], kg[b,j,:]) : 0
// ---------------------------------------------------------------------------
__global__ __launch_bounds__(256)
void buildM_kernel(const float* __restrict__ qg, const float* __restrict__ kg,
                   const float* __restrict__ k_base,
                   const float* __restrict__ gate_logit,
                   const float* __restrict__ alpha_logit,
                   bf16* __restrict__ M) {
    int b = blockIdx.z;
    int ti = blockIdx.y, tj = blockIdx.x;
    int i0 = ti * 32, j0 = tj * 32;
    int tx = threadIdx.x, ty = threadIdx.y;
    bf16* Mb = M + (size_t)b * W_ * W_;
    const bf16 zero = __float2bfloat16(0.f);

    if (tj > ti) {
#pragma unroll
        for (int a = 0; a < 2; ++a)
#pragma unroll
            for (int c = 0; c < 2; ++c)
                Mb[(size_t)(i0 + ty * 2 + a) * W_ + (j0 + tx * 2 + c)] = zero;
        return;
    }

    __shared__ float Qs[32][65];
    __shared__ float Ks[32][65];
    int tid = ty * 16 + tx;
    for (int e = tid; e < 32 * 64; e += 256) {
        int rr = e & 63, row = e >> 6;
        Qs[row][rr] = qg[((size_t)b * W_ + i0 + row) * R_ + rr];
        Ks[row][rr] = kg[((size_t)b * W_ + j0 + row) * R_ + rr];
    }
    __syncthreads();

    float acc[2][2] = {{0.f, 0.f}, {0.f, 0.f}};
#pragma unroll 8
    for (int r = 0; r < 64; ++r) {
        float qa = Qs[ty * 2 + 0][r], qb = Qs[ty * 2 + 1][r];
        float ka = Ks[tx * 2 + 0][r], kb = Ks[tx * 2 + 1][r];
        acc[0][0] += qa * ka; acc[0][1] += qa * kb;
        acc[1][0] += qb * ka; acc[1][1] += qb * kb;
    }

    float gate  = 1.f / (1.f + expf(-(*gate_logit)));
    float alpha = 1.f / (1.f + expf(-(*alpha_logit)));  // ALPHA_CAP = 1
#pragma unroll
    for (int a = 0; a < 2; ++a) {
#pragma unroll
        for (int c = 0; c < 2; ++c) {
            int i = i0 + ty * 2 + a, j = j0 + tx * 2 + c;
            float vkb = k_base[(size_t)i * W_ + j];
            float out = (j <= i) ? (gate * vkb + alpha * acc[a][c]) : 0.f;
            Mb[(size_t)i * W_ + j] = __float2bfloat16(out);
        }
    }
}

// ---------------------------------------------------------------------------
// MFMA GEMM: C[m,n] = sum_k A[m,k]*B[n,k]  (A, B bf16, k-major)
// BM=BN=128, BK=32 — round-9 proven config (tile/traffic/loop unchanged).
// *** Round-12 change: 512 THREADS = 8 WAVES per block (was 4). Evidence
// r8-r12: dispatcher caps at 2 blocks/CU regardless of grid; MfmaUtil tracks
// waves/CU (m97: 37% @16 waves, us: 17% @8). Packing 8 waves/block doubles
// waves/CU (2 blk x 8 = 16) with IDENTICAL per-block traffic, LDS (32 KB),
// and barrier structure — pure TLP to cover the ~900-cyc A-load latency. ***
// Wave w (0-7): subtile rows wy*32 (wy=w>>1), cols wx*64 (wx=w&1) -> 2x4
// MFMA frags (acc 8 x f32x4). Staging: wave w stages A rows [w*16,w*16+16)
// and B rows [w*16,w*16+16), 1 async16 each. XOR-swizzled (conflict-free),
// hoisted pointers, LDS dbuf, one __syncthreads per iter.
// Grid XCD-TRANSPOSED: x = M-stripe (count % 8 == 0), y = N-block.
// SK>1: z = K-chunk, EPI must be 5.  SK==1: z = batch.
// EPI 0: Cout bf16 = acc                      (batched store via sC)
// EPI 1: Cout fp32 = acc + bias[n] + Res[idx] (Res may alias Cout, same-idx)
// EPI 2: Cout bf16 = gelu_exact(acc + bias[n])
// EPI 5: Cout fp32 partial at z*sC            (deterministic split-K)
// ---------------------------------------------------------------------------
template<int EPI, int SK>
__global__ __launch_bounds__(512)
void mgemm_kernel(const bf16* __restrict__ A, const bf16* __restrict__ Bm,
                  const float* __restrict__ Res, const float* __restrict__ bias,
                  void* __restrict__ Cout,
                  int M, int N, int K,
                  long sA, long sB, long sC, int causal) {
    __shared__ __align__(16) short At[2][128 * 32];
    __shared__ __align__(16) short Bt[2][128 * 32];
    int z = blockIdx.z;
    const bf16* Ab = (SK > 1) ? A : A + (size_t)z * sA;
    const bf16* Bb = (SK > 1) ? Bm : Bm + (size_t)z * sB;
    int kchunk = K / SK;
    int kbeg = (SK > 1) ? z * kchunk : 0;
    int m0 = blockIdx.x * 128, n0 = blockIdx.y * 128;   // transposed grid
    int tid = threadIdx.x;
    int lane = tid & 63, wave = tid >> 6;               // wave 0..7
    int wy = wave >> 1, wx = wave & 1;
    int quad = lane >> 4, l15 = lane & 15;

    f32x4 acc[2][4];
#pragma unroll
    for (int i = 0; i < 2; ++i)
#pragma unroll
        for (int j = 0; j < 4; ++j)
            acc[i][j] = (f32x4){0.f, 0.f, 0.f, 0.f};

    int kend = kbeg + kchunk;
    if (SK == 1 && causal) kend = (m0 + 128 < K) ? m0 + 128 : K;
    int nIter = (kend - kbeg) >> 5;

    // staging: wave w covers rows [w*16, w*16+16); lane -> row w*16+(lane>>2),
    // 16B chunk slot lane&3, source chunk XOR-swizzled (b128 reads 2-way max).
    int srcChunk = ((lane & 3) ^ ((lane >> 3) & 3)) * 8;
    size_t rowA = (size_t)(m0 + wave * 16 + (lane >> 2)) * K;
    size_t rowB = (size_t)(n0 + wave * 16 + (lane >> 2)) * K;
    const bf16* aP = Ab + rowA + srcChunk + kbeg;
    const bf16* bP = Bb + rowB + srcChunk + kbeg;
    short* dA[2] = { &At[0][wave * 512], &At[1][wave * 512] };
    short* dB[2] = { &Bt[0][wave * 512], &Bt[1][wave * 512] };

    int rswz = (quad ^ ((l15 >> 1) & 3)) * 8;

    // prologue: stage tile 0 into buf 0
    async16(aP, dA[0]);
    async16(bP, dB[0]);
    aP += 32; bP += 32;
    __syncthreads();

    for (int it = 0; it < nIter; ++it) {
        int cur = it & 1;
        if (it + 1 < nIter) {
            int nxt = cur ^ 1;
            async16(aP, dA[nxt]);
            async16(bP, dB[nxt]);
            aP += 32; bP += 32;
        }
        bf16x8 af[2], bfr[4];
#pragma unroll
        for (int mi = 0; mi < 2; ++mi)
            af[mi] = *(const bf16x8*)&At[cur][(wy * 32 + mi * 16 + l15) * 32 + rswz];
#pragma unroll
        for (int ni = 0; ni < 4; ++ni)
            bfr[ni] = *(const bf16x8*)&Bt[cur][(wx * 64 + ni * 16 + l15) * 32 + rswz];
#pragma unroll
        for (int mi = 0; mi < 2; ++mi)
#pragma unroll
            for (int ni = 0; ni < 4; ++ni)
                acc[mi][ni] = __builtin_amdgcn_mfma_f32_16x16x32_bf16(
                    af[mi], bfr[ni], acc[mi][ni], 0, 0, 0);
        // one barrier/iter: (a) next-buf async complete, (b) cur reads done
        __syncthreads();
    }

    // ---- epilogue ----
#pragma unroll
    for (int ni = 0; ni < 4; ++ni) {
        int col = n0 + wx * 64 + ni * 16 + l15;
        float bv = (EPI == 1 || EPI == 2) ? bias[col] : 0.f;
#pragma unroll
        for (int mi = 0; mi < 2; ++mi) {
            int row0 = m0 + wy * 32 + mi * 16 + quad * 4;
#pragma unroll
            for (int r = 0; r < 4; ++r) {
                size_t idx = (size_t)(row0 + r) * N + col;
                float val = acc[mi][ni][r];
                if constexpr (EPI == 0) {
                    ((bf16*)Cout)[(size_t)z * sC + idx] = __float2bfloat16(val);
                } else if constexpr (EPI == 1) {
                    ((float*)Cout)[idx] = val + bv + Res[idx];
                } else if constexpr (EPI == 2) {
                    val += bv;
                    val = 0.5f * val * (1.f + erff(val * 0.70710678118654752f));
                    ((bf16*)Cout)[idx] = __float2bfloat16(val);
                } else {
                    ((float*)Cout)[(size_t)z * sC + idx] = val;
                }
            }
        }
    }
}

// ---------------------------------------------------------------------------
// Workspace (peak 62 MB):
//   [0,16)  : hnorm bf16 -> attn bf16 (step4 out) -> mnorm bf16 (step6 out)
//   [16,18) : uvT bf16 (dead after step 2) -> qg fp32 (written step 2b)
//   [18,20) : kg fp32
//   [20,36) : hnormT bf16            -+ tbuf bf16 [20,52) after step 4
//   [36,52) : qkraw fp32 4x4MB split-K partials (dead after 2b) -> Mbuf bf16
//   [52,54) : proj_w bf16   [54,58): up_w bf16   [58,62): down_w bf16
//   h1 lives in d_out (fp32); step 8 does same-index RMW (alias-safe).
// ---------------------------------------------------------------------------
extern "C" void kernel_launch(void* const* d_in, const int* in_sizes, int n_in,
                              void* d_out, int out_size, void* d_ws, size_t ws_size,
                              hipStream_t stream) {
    const float* h           = (const float*)d_in[0];
    const float* k_base      = (const float*)d_in[1];
    const float* decay_logit = (const float*)d_in[2];
    const float* gate_logit  = (const float*)d_in[3];
    const float* alpha_logit = (const float*)d_in[4];
    const float* u           = (const float*)d_in[5];
    const float* v           = (const float*)d_in[6];
    const float* proj_w      = (const float*)d_in[7];
    const float* proj_b      = (const float*)d_in[8];
    const float* norm1_scale = (const float*)d_in[9];
    const float* norm2_scale = (const float*)d_in[10];
    const float* up_w        = (const float*)d_in[11];
    const float* up_b        = (const float*)d_in[12];
    const float* down_w      = (const float*)d_in[13];
    const float* down_b      = (const float*)d_in[14];

    const size_t MB = 1048576;
    char* ws = (char*)d_ws;
    bf16*  hnorm   = (bf16*)(ws);                  // 16 MB
    bf16*  uvT     = (bf16*)(ws + 16 * MB);        // 256 KB (dead after step 2)
    float* qg      = (float*)(ws + 16 * MB);       //  2 MB (written step 2b)
    float* kg      = (float*)(ws + 18 * MB);       //  2 MB
    bf16*  hnormT  = (bf16*)(ws + 20 * MB);        // 16 MB
    float* qkraw   = (float*)(ws + 36 * MB);       // 16 MB partials (pre-buildM)
    bf16*  Mbuf    = (bf16*)(ws + 36 * MB);        // 16 MB (step 3 out)
    bf16*  proj_wb = (bf16*)(ws + 52 * MB);        //  2 MB
    bf16*  up_wb   = (bf16*)(ws + 54 * MB);        //  4 MB
    bf16*  down_wb = (bf16*)(ws + 58 * MB);        //  4 MB
    bf16*  attn    = hnorm;                        // [0,16) after qk GEMM
    bf16*  mnorm   = hnorm;
    bf16*  tbuf    = hnormT;                       // [20,52) after step 4
    float* h1      = (float*)d_out;

    // 0. weight conversions (single launch) + uvT
    convert3_kernel<<<5 * D_ * D_ / 2048, 256, 0, stream>>>(
        proj_w, up_w, down_w, proj_wb, up_wb, down_wb);
    uvT_kernel<<<dim3(D_ / 64, 1, 2), 256, 0, stream>>>(u, v, uvT);

    // 1. h_norm = rmsnorm(h, norm1_scale)
    rmsnorm_kernel<<<B_ * W_, 256, 0, stream>>>(h, norm1_scale, hnorm);

    // 1b. hnormT[b][d][j] = hnorm[b][j][d]
    transpose_kernel<<<dim3(W_ / 64, D_ / 64, B_), 256, 0, stream>>>(hnorm, hnormT);

    // 2. qkraw[z] = hnorm @ [u|v] K-chunk z (deterministic split-K=4)
    mgemm_kernel<5, 4><<<dim3(B_ * W_ / 128, 1, 4), 512, 0, stream>>>(
        hnorm, uvT, nullptr, nullptr, qkraw, B_ * W_, 128, D_,
        0, 0, (long)B_ * W_ * 128, 0);

    // 2b. sum partials, l2norm halves, gamma^{+/-i} -> qg, kg (fp32)
    qk_epilogue_kernel<<<B_ * W_, 128, 0, stream>>>(qkraw, decay_logit, qg, kg);

    // 3. M = causal * (gate*k_base + alpha*scores)
    buildM_kernel<<<dim3(W_ / 32, W_ / 32, B_), dim3(16, 16), 0, stream>>>(
        qg, kg, k_base, gate_logit, alpha_logit, Mbuf);

    // 4. attn = M @ hnorm  (B = hnormT, batched via z, causal k-trunc)
    mgemm_kernel<0, 1><<<dim3(W_ / 128, D_ / 128, B_), 512, 0, stream>>>(
        Mbuf, hnormT, nullptr, nullptr, attn, W_, D_, W_,
        (long)W_ * W_, (long)W_ * D_, (long)W_ * D_, 1);

    // 5. h1 = h + attn @ proj_w^T + proj_b   -> d_out (fp32)
    mgemm_kernel<1, 1><<<dim3(B_ * W_ / 128, D_ / 128, 1), 512, 0, stream>>>(
        attn, proj_wb, h, proj_b, h1, B_ * W_, D_, D_, 0, 0, 0, 0);

    // 6. mnorm = rmsnorm(h1, norm2_scale)
    rmsnorm_kernel<<<B_ * W_, 256, 0, stream>>>(h1, norm2_scale, mnorm);

    // 7. t = gelu(mnorm @ up_w^T + up_b)     -> tbuf (bf16)
    mgemm_kernel<2, 1><<<dim3(B_ * W_ / 128, 2 * D_ / 128, 1), 512, 0, stream>>>(
        mnorm, up_wb, nullptr, up_b, tbuf, B_ * W_, 2 * D_, D_, 0, 0, 0, 0);

    // 8. out = h1 + t @ down_w^T + down_b  (h1 aliases d_out, same-idx RMW)
    mgemm_kernel<1, 1><<<dim3(B_ * W_ / 128, D_ / 128, 1), 512, 0, stream>>>(
        tbuf, down_wb, h1, down_b, (float*)d_out, B_ * W_, D_, 2 * D_, 0, 0, 0, 0);
}